// Round 1
// 690.055 us; speedup vs baseline: 1.3195x; 1.3195x over previous
//
#include <hip/hip_runtime.h>

typedef unsigned short u16;
typedef unsigned int u32;
typedef short short8 __attribute__((ext_vector_type(8)));
typedef float floatx4 __attribute__((ext_vector_type(4)));

__device__ __forceinline__ float bf2f(u16 x) { return __uint_as_float(((u32)x) << 16); }
__device__ __forceinline__ u16 f2bf(float x) {
    u32 u = __float_as_uint(x);
    u += 0x7fffu + ((u >> 16) & 1u);
    return (u16)(u >> 16);
}

// ---------------- diagnostic: zero the output (fp32) ----------------
__global__ void zero_out_k(float* __restrict__ out, int n) {
    int i = blockIdx.x * 256 + threadIdx.x;
    if (i < n) out[i] = 0.f;
}

// ---------------- CSR build: histogram+rank, scan, rank-scatter ----------------

// rank[e] = position of edge e within its dst segment (u16: max degree ~60 here)
__global__ void hist_rank_k(const int* __restrict__ dst, int* __restrict__ cnt,
                            u16* __restrict__ rank, int E, int N) {
    int e = blockIdx.x * 256 + threadIdx.x;
    if (e < E) {
        int d = dst[e];
        d = d < 0 ? 0 : (d >= N ? N - 1 : d);
        rank[e] = (u16)atomicAdd(&cnt[d], 1);
    }
}

__global__ void scan1_k(const int* __restrict__ cnt, int* __restrict__ excl,
                        int* __restrict__ aux, int N) {
    __shared__ int tmp[1024];
    int t = threadIdx.x;
    int i = blockIdx.x * 1024 + t;
    int v = (i < N) ? cnt[i] : 0;
    tmp[t] = v;
    __syncthreads();
    for (int off = 1; off < 1024; off <<= 1) {
        int x = (t >= off) ? tmp[t - off] : 0;
        __syncthreads();
        tmp[t] += x;
        __syncthreads();
    }
    if (i < N) excl[i] = tmp[t] - v;
    if (t == 1023) aux[blockIdx.x] = tmp[t];
}

__global__ void scan2_k(int* __restrict__ aux, int nb) {
    int lane = threadIdx.x;  // single block of 64; nb <= 128
    int v0 = (lane < nb) ? aux[lane] : 0;
    int v1 = (lane + 64 < nb) ? aux[lane + 64] : 0;
    int s0 = v0;
    for (int off = 1; off < 64; off <<= 1) { int x = __shfl_up(s0, off); if (lane >= off) s0 += x; }
    int total0 = __shfl(s0, 63);
    int s1 = v1;
    for (int off = 1; off < 64; off <<= 1) { int x = __shfl_up(s1, off); if (lane >= off) s1 += x; }
    if (lane < nb) aux[lane] = s0 - v0;
    if (lane + 64 < nb) aux[lane + 64] = total0 + s1 - v1;
}

__global__ void scan3_k(const int* __restrict__ excl, const int* __restrict__ aux,
                        int* __restrict__ offs, int N, int E) {
    int i = blockIdx.x * 1024 + threadIdx.x;
    if (i < N) {
        offs[i] = excl[i] + aux[blockIdx.x];
    } else if (i == N) {
        offs[N] = E;
    }
}

// Atomic-free scatter: esrc[offs[d] + rank[e]] = src[e].
// NPASS dst-range passes confine the random-write window to ~E/NPASS*4 bytes so
// partial lines merge in L2 before HBM writeback. adj re-reads hit L3.
template <int NPASS>
__global__ __launch_bounds__(256) void scatter_nr_k(const int* __restrict__ src,
                                                    const int* __restrict__ dst,
                                                    const u16* __restrict__ rank,
                                                    const int* __restrict__ offs,
                                                    int* __restrict__ esrc, int E, int N) {
    const int stride = gridDim.x * 256;
    const int t0 = blockIdx.x * 256 + threadIdx.x;
    const int span = (N + NPASS - 1) / NPASS;
#pragma unroll 1
    for (int p = 0; p < NPASS; ++p) {
        const int lo = p * span, hi = lo + span;
        for (int e = t0; e < E; e += stride) {
            int d = dst[e];
            d = d < 0 ? 0 : (d >= N ? N - 1 : d);
            if (d >= lo && d < hi) {
                int s = src[e];
                s = s < 0 ? 0 : (s >= N ? N - 1 : s);
                esrc[offs[d] + (int)rank[e]] = s;
            }
        }
    }
}

// ---------------- weight prepack (fp32 -> bf16 MFMA-fragment order) ----------------
// Wf[(kq*DO + n)*8 + j] = bf16(W[(kq*8 + j)*DO + n])   (k = kq*8 + j)
__global__ void prepack_k(const float* __restrict__ W, u16* __restrict__ Wf, int DO, int total) {
    int idx = blockIdx.x * 256 + threadIdx.x;
    if (idx >= total) return;
    int j = idx & 7;
    int t = idx >> 3;
    int n = t % DO;
    int kq = t / DO;
    Wf[idx] = f2bf(W[(size_t)(kq * 8 + j) * DO + n]);
}

// ---------------- GEMM + fused alpha dots ----------------
// H = X @ W (bf16 MFMA, fp32 acc); AS/AD = H . a_src/a_dst from fp32 accs.
// F32IN: X fp32 (convert during staging) else bf16. H32: store H fp32 else bf16.
template <int K, int DO, bool F32IN, bool H32>
__global__ __launch_bounds__(256, 2) void gemm_k(const void* __restrict__ Xv,
                                                 const u16* __restrict__ Wf,
                                                 void* __restrict__ Hv,
                                                 const float* __restrict__ a_src,
                                                 const float* __restrict__ a_dst,
                                                 float* __restrict__ AS,
                                                 float* __restrict__ AD, int nrow) {
    constexpr int BM = 128, BK = 64;
    __shared__ alignas(16) u16 At[BM * BK];  // 16 KB bf16, XOR-swizzled 16B units
    const int tid = threadIdx.x;
    const int wave = tid >> 6, lane = tid & 63;
    const int quad = lane >> 4, l16 = lane & 15;
    const int row0 = blockIdx.x * BM;

    floatx4 acc[2][DO / 16];
#pragma unroll
    for (int a = 0; a < 2; a++)
#pragma unroll
        for (int b = 0; b < DO / 16; b++) acc[a][b] = floatx4{0.f, 0.f, 0.f, 0.f};

    for (int kt = 0; kt < K / BK; ++kt) {
        __syncthreads();
#pragma unroll
        for (int i = 0; i < 4; ++i) {
            int seg = tid + i * 256;          // 1024 segments of 8 k-elements
            int r = seg >> 3, c = seg & 7;
            int gr = row0 + r;
            gr = gr < nrow ? gr : nrow - 1;   // clamp (pad rows discarded on store)
            u16 pk[8];
            if (F32IN) {
                const float* X = (const float*)Xv;
                float4 v0 = *(const float4*)(X + (size_t)gr * K + kt * BK + c * 8);
                float4 v1 = *(const float4*)(X + (size_t)gr * K + kt * BK + c * 8 + 4);
                pk[0] = f2bf(v0.x); pk[1] = f2bf(v0.y); pk[2] = f2bf(v0.z); pk[3] = f2bf(v0.w);
                pk[4] = f2bf(v1.x); pk[5] = f2bf(v1.y); pk[6] = f2bf(v1.z); pk[7] = f2bf(v1.w);
                *(int4*)(At + r * BK + (c ^ (r & 7)) * 8) = *(const int4*)pk;
            } else {
                const u16* X = (const u16*)Xv;
                int4 v = *(const int4*)(X + (size_t)gr * K + kt * BK + c * 8);
                *(int4*)(At + r * BK + (c ^ (r & 7)) * 8) = v;
            }
        }
        __syncthreads();
#pragma unroll
        for (int ks = 0; ks < 2; ++ks) {
            short8 bfr[DO / 16];
            int kq = kt * 8 + ks * 4 + quad;
#pragma unroll
            for (int ct = 0; ct < DO / 16; ++ct)
                bfr[ct] = *(const short8*)(Wf + ((size_t)kq * DO + ct * 16 + l16) * 8);
#pragma unroll
            for (int rt = 0; rt < 2; ++rt) {
                int row = wave * 32 + rt * 16 + l16;
                int unit = (ks * 4 + quad) ^ (row & 7);
                short8 afr = *(const short8*)(At + row * BK + unit * 8);
#pragma unroll
                for (int ct = 0; ct < DO / 16; ++ct)
                    acc[rt][ct] =
                        __builtin_amdgcn_mfma_f32_16x16x32_bf16(afr, bfr[ct], acc[rt][ct], 0, 0, 0);
            }
        }
    }
    // Epilogue. C/D layout: col = ct*16 + l16, row = quad*4 + r  [m89/m91 verified].
    // Fused alpha dots: partial over this lane's 8 (or 4) cols, reduce across l16 group.
    float asv[DO / 16], adv[DO / 16];
#pragma unroll
    for (int ct = 0; ct < DO / 16; ++ct) {
        asv[ct] = a_src[ct * 16 + l16];
        adv[ct] = a_dst[ct * 16 + l16];
    }
#pragma unroll
    for (int rt = 0; rt < 2; ++rt)
#pragma unroll
        for (int r = 0; r < 4; ++r) {
            int grow = row0 + wave * 32 + rt * 16 + quad * 4 + r;
            bool ok = grow < nrow;
            float ps = 0.f, pd = 0.f;
#pragma unroll
            for (int ct = 0; ct < DO / 16; ++ct) {
                float v = acc[rt][ct][r];
                ps = fmaf(v, asv[ct], ps);
                pd = fmaf(v, adv[ct], pd);
                if (ok) {
                    if (H32)
                        ((float*)Hv)[(size_t)grow * DO + ct * 16 + l16] = v;
                    else
                        ((u16*)Hv)[(size_t)grow * DO + ct * 16 + l16] = f2bf(v);
                }
            }
            // reduce over the 16-lane col group (xor bits 0-3 stay within quad)
#pragma unroll
            for (int o = 1; o < 16; o <<= 1) {
                ps += __shfl_xor(ps, o);
                pd += __shfl_xor(pd, o);
            }
            if (ok && l16 == 0) {
                AS[grow] = ps;
                AD[grow] = pd;
            }
        }
}

// ---------------- fused segment softmax + aggregate (one wave per dst node) ----------------
// HB: h rows are bf16 (else fp32). OUTB: write bf16 packed (else fp32).
template <int DO, bool HB, bool OUTB>
__global__ __launch_bounds__(256) void agg_k(const void* __restrict__ Hv,
                                             const float* __restrict__ AS,
                                             const float* __restrict__ AD,
                                             const int* __restrict__ offs,
                                             const int* __restrict__ esrc,
                                             const float* __restrict__ bias,
                                             void* __restrict__ OUT, int N) {
    const int wave = threadIdx.x >> 6, lane = threadIdx.x & 63;
    const int d = blockIdx.x * 4 + wave;
    if (d >= N) return;
    const int o0 = offs[d];
    const int deg = offs[d + 1] - o0;  // real in-edges
    const int tot = deg + 1;           // + self loop
    const float ad = AD[d];

    float acc0 = 0.f, acc1 = 0.f;

    // one edge's contribution: gather row sl, fma with broadcast weight wl
    auto body = [&](float wl, int sl) {
        if (DO == 128) {
            if (HB) {
                u32 hv = ((const u32*)Hv)[(size_t)sl * 64 + lane];
                acc0 = fmaf(wl, bf2f((u16)hv), acc0);
                acc1 = fmaf(wl, bf2f((u16)(hv >> 16)), acc1);
            } else {
                float2 hv = ((const float2*)Hv)[(size_t)sl * 64 + lane];
                acc0 = fmaf(wl, hv.x, acc0);
                acc1 = fmaf(wl, hv.y, acc1);
            }
        } else {
            if (HB) {
                acc0 = fmaf(wl, bf2f(((const u16*)Hv)[(size_t)sl * DO + lane]), acc0);
            } else {
                acc0 = fmaf(wl, ((const float*)Hv)[(size_t)sl * DO + lane], acc0);
            }
        }
    };

    if (tot <= 64) {
        // ---- fast path: whole segment resident in one wave, single gather pass ----
        int s = (lane < deg) ? esrc[o0 + lane] : d;  // lane==deg -> self loop
        bool valid = lane < tot;
        float lg = AS[s] + ad;
        lg = lg > 0.f ? lg : lg * 0.2f;
        float lgv = valid ? lg : -1e30f;
        float m = lgv;
        for (int o = 32; o; o >>= 1) m = fmaxf(m, __shfl_xor(m, o));
        float e = valid ? __expf(lg - m) : 0.f;
        float sum = e;
        for (int o = 32; o; o >>= 1) sum += __shfl_xor(sum, o);
        float w = e * (1.f / sum);
        // unroll x4: 4 independent row-gathers in flight per wave (latency hiding)
        int l = 0;
        for (; l + 3 < tot; l += 4) {
            float w0 = __shfl(w, l + 0), w1 = __shfl(w, l + 1);
            float w2 = __shfl(w, l + 2), w3 = __shfl(w, l + 3);
            int q0 = __shfl(s, l + 0), q1 = __shfl(s, l + 1);
            int q2 = __shfl(s, l + 2), q3 = __shfl(s, l + 3);
            body(w0, q0);
            body(w1, q1);
            body(w2, q2);
            body(w3, q3);
        }
        for (; l < tot; ++l) body(__shfl(w, l), __shfl(s, l));
    } else {
        // ---- general path (deg > 63): 3-pass ----
        float mx = -1e30f;
        for (int i = lane; i < tot; i += 64) {
            int s = (i < deg) ? esrc[o0 + i] : d;
            float lg = AS[s] + ad;
            lg = lg > 0.f ? lg : lg * 0.2f;
            mx = fmaxf(mx, lg);
        }
        for (int o = 32; o; o >>= 1) mx = fmaxf(mx, __shfl_xor(mx, o));
        float sum = 0.f;
        for (int i = lane; i < tot; i += 64) {
            int s = (i < deg) ? esrc[o0 + i] : d;
            float lg = AS[s] + ad;
            lg = lg > 0.f ? lg : lg * 0.2f;
            sum += __expf(lg - mx);
        }
        for (int o = 32; o; o >>= 1) sum += __shfl_xor(sum, o);
        const float inv = 1.f / sum;
        for (int c0 = 0; c0 < tot; c0 += 64) {
            int i = c0 + lane;
            float w = 0.f;
            int s = d;
            if (i < tot) {
                s = (i < deg) ? esrc[o0 + i] : d;
                float lg = AS[s] + ad;
                lg = lg > 0.f ? lg : lg * 0.2f;
                w = __expf(lg - mx) * inv;
            }
            int cn = tot - c0;
            cn = cn < 64 ? cn : 64;
            int l = 0;
            for (; l + 3 < cn; l += 4) {
                float w0 = __shfl(w, l + 0), w1 = __shfl(w, l + 1);
                float w2 = __shfl(w, l + 2), w3 = __shfl(w, l + 3);
                int q0 = __shfl(s, l + 0), q1 = __shfl(s, l + 1);
                int q2 = __shfl(s, l + 2), q3 = __shfl(s, l + 3);
                body(w0, q0);
                body(w1, q1);
                body(w2, q2);
                body(w3, q3);
            }
            for (; l < cn; ++l) body(__shfl(w, l), __shfl(s, l));
        }
    }

    // epilogue: + bias, leaky_relu(0.25), store
    if (DO == 128) {
        int f = 2 * lane;
        float v0 = acc0 + bias[f];
        float v1 = acc1 + bias[f + 1];
        v0 = v0 > 0.f ? v0 : v0 * 0.25f;
        v1 = v1 > 0.f ? v1 : v1 * 0.25f;
        if (OUTB) {
            u32 packed = (u32)f2bf(v0) | ((u32)f2bf(v1) << 16);
            ((u32*)OUT)[(size_t)d * 64 + lane] = packed;
        } else {
            ((float2*)OUT)[(size_t)d * 64 + lane] = float2{v0, v1};
        }
    } else {
        float v0 = acc0 + bias[lane];
        v0 = v0 > 0.f ? v0 : v0 * 0.25f;
        if (OUTB) {
            ((u16*)OUT)[(size_t)d * DO + lane] = f2bf(v0);
        } else {
            ((float*)OUT)[(size_t)d * DO + lane] = v0;
        }
    }
}

// ---------------- launch ----------------

extern "C" void kernel_launch(void* const* d_in, const int* in_sizes, int n_in,
                              void* d_out, int out_size, void* d_ws, size_t ws_size,
                              hipStream_t stream) {
    const int N = in_sizes[0] / 512;  // 100000
    const int E = in_sizes[1] / 2;    // 1600000

    const float* data = (const float*)d_in[0];
    const int* adj = (const int*)d_in[1];
    const float* W1 = (const float*)d_in[2];
    const float* as1 = (const float*)d_in[3];
    const float* ad1 = (const float*)d_in[4];
    const float* b1 = (const float*)d_in[5];
    const float* W2 = (const float*)d_in[6];
    const float* as2 = (const float*)d_in[7];
    const float* ad2 = (const float*)d_in[8];
    const float* b2 = (const float*)d_in[9];
    const float* W3 = (const float*)d_in[10];
    const float* as3 = (const float*)d_in[11];
    const float* ad3 = (const float*)d_in[12];
    const float* b3 = (const float*)d_in[13];

    // ---- workspace carve + budget check ----
    char* ws = (char*)d_ws;
    size_t need = 0;
    auto carve = [&](size_t bytes) {
        void* p = (void*)(ws + need);
        need += (bytes + 255) & ~(size_t)255;
        return p;
    };
    int* esrc = (int*)carve((size_t)E * 4);
    int* offs = (int*)carve((size_t)(N + 1) * 4);
    int* cnt = (int*)carve((size_t)N * 4);
    int* excl = (int*)carve((size_t)N * 4);
    int* aux = (int*)carve(1024);
    float* AS = (float*)carve((size_t)N * 4);
    float* AD = (float*)carve((size_t)N * 4);
    u16* Hb = (u16*)carve((size_t)N * 128 * 2);  // bf16 h (layers 1-2)
    float* H32 = (float*)Hb;                     // fp32 h for layer 3 (DO=64): same 25.6 MB
    u16* x1 = (u16*)carve((size_t)N * 128 * 2);  // bf16 next-layer input
    u16* x2 = x1;                                // x1 dead after layer-2 GEMM
    u16* Wf1 = (u16*)carve(512 * 128 * 2);
    u16* Wf2 = (u16*)carve(128 * 128 * 2);
    u16* Wf3 = (u16*)carve(128 * 64 * 2);

    // rank lives in Hb: written by hist, consumed by scatter, both before gemm1 writes Hb
    u16* rank = (u16*)Hb;

    if (need > ws_size) {
        // Diagnostic signature: absmax == ref absmax (0.2373) => ws too small.
        zero_out_k<<<(out_size + 255) / 256, 256, 0, stream>>>((float*)d_out, out_size);
        return;
    }

    const int* srcl = adj;
    const int* dstl = adj + E;

    // ---- CSR build (once, reused by all 3 layers) ----
    hipMemsetAsync(cnt, 0, (size_t)N * 4, stream);
    hist_rank_k<<<(E + 255) / 256, 256, 0, stream>>>(dstl, cnt, rank, E, N);
    int nb = (N + 1023) / 1024;
    scan1_k<<<nb, 1024, 0, stream>>>(cnt, excl, aux, N);
    scan2_k<<<1, 64, 0, stream>>>(aux, nb);
    scan3_k<<<nb, 1024, 0, stream>>>(excl, aux, offs, N, E);
    scatter_nr_k<8><<<2048, 256, 0, stream>>>(srcl, dstl, rank, offs, esrc, E, N);

    // ---- weight prepack (fp32 -> bf16 fragments) ----
    prepack_k<<<(512 * 128 + 255) / 256, 256, 0, stream>>>(W1, Wf1, 128, 512 * 128);
    prepack_k<<<(128 * 128 + 255) / 256, 256, 0, stream>>>(W2, Wf2, 128, 128 * 128);
    prepack_k<<<(128 * 64 + 255) / 256, 256, 0, stream>>>(W3, Wf3, 64, 128 * 64);

    const int gblk = (N + 127) / 128;
    const int nblk = (N + 3) / 4;

    // ---- layer 1 ----
    gemm_k<512, 128, true, false><<<gblk, 256, 0, stream>>>(data, Wf1, Hb, as1, ad1, AS, AD, N);
    agg_k<128, true, true><<<nblk, 256, 0, stream>>>(Hb, AS, AD, offs, esrc, b1, x1, N);
    // ---- layer 2 ----
    gemm_k<128, 128, false, false><<<gblk, 256, 0, stream>>>(x1, Wf2, Hb, as2, ad2, AS, AD, N);
    agg_k<128, true, true><<<nblk, 256, 0, stream>>>(Hb, AS, AD, offs, esrc, b2, x2, N);
    // ---- layer 3 (fp32 h for final accuracy; 256 B/row gather either way) ----
    gemm_k<128, 64, false, true><<<gblk, 256, 0, stream>>>(x2, Wf3, H32, as3, ad3, AS, AD, N);
    agg_k<64, false, false><<<nblk, 256, 0, stream>>>(H32, AS, AD, offs, esrc, b3, d_out, N);
}

// Round 2
// 685.707 us; speedup vs baseline: 1.3279x; 1.0063x over previous
//
#include <hip/hip_runtime.h>

typedef unsigned short u16;
typedef unsigned int u32;
typedef short short8 __attribute__((ext_vector_type(8)));
typedef float floatx4 __attribute__((ext_vector_type(4)));

__device__ __forceinline__ float bf2f(u16 x) { return __uint_as_float(((u32)x) << 16); }
__device__ __forceinline__ u16 f2bf(float x) {
    u32 u = __float_as_uint(x);
    u += 0x7fffu + ((u >> 16) & 1u);
    return (u16)(u >> 16);
}

// ---------------- diagnostic: zero the output (fp32) ----------------
__global__ void zero_out_k(float* __restrict__ out, int n) {
    int i = blockIdx.x * 256 + threadIdx.x;
    if (i < n) out[i] = 0.f;
}

// ---------------- CSR build: histogram+rank, scan, rank-scatter ----------------

// rank[e] = position of edge e within its dst segment (u16: max degree ~60 here)
__global__ void hist_rank_k(const int* __restrict__ dst, int* __restrict__ cnt,
                            u16* __restrict__ rank, int E, int N) {
    int e = blockIdx.x * 256 + threadIdx.x;
    if (e < E) {
        int d = dst[e];
        d = d < 0 ? 0 : (d >= N ? N - 1 : d);
        rank[e] = (u16)atomicAdd(&cnt[d], 1);
    }
}

__global__ void scan1_k(const int* __restrict__ cnt, int* __restrict__ excl,
                        int* __restrict__ aux, int N) {
    __shared__ int tmp[1024];
    int t = threadIdx.x;
    int i = blockIdx.x * 1024 + t;
    int v = (i < N) ? cnt[i] : 0;
    tmp[t] = v;
    __syncthreads();
    for (int off = 1; off < 1024; off <<= 1) {
        int x = (t >= off) ? tmp[t - off] : 0;
        __syncthreads();
        tmp[t] += x;
        __syncthreads();
    }
    if (i < N) excl[i] = tmp[t] - v;
    if (t == 1023) aux[blockIdx.x] = tmp[t];
}

__global__ void scan2_k(int* __restrict__ aux, int nb) {
    int lane = threadIdx.x;  // single block of 64; nb <= 128
    int v0 = (lane < nb) ? aux[lane] : 0;
    int v1 = (lane + 64 < nb) ? aux[lane + 64] : 0;
    int s0 = v0;
    for (int off = 1; off < 64; off <<= 1) { int x = __shfl_up(s0, off); if (lane >= off) s0 += x; }
    int total0 = __shfl(s0, 63);
    int s1 = v1;
    for (int off = 1; off < 64; off <<= 1) { int x = __shfl_up(s1, off); if (lane >= off) s1 += x; }
    if (lane < nb) aux[lane] = s0 - v0;
    if (lane + 64 < nb) aux[lane + 64] = total0 + s1 - v1;
}

__global__ void scan3_k(const int* __restrict__ excl, const int* __restrict__ aux,
                        int* __restrict__ offs, int N, int E) {
    int i = blockIdx.x * 1024 + threadIdx.x;
    if (i < N) {
        offs[i] = excl[i] + aux[blockIdx.x];
    } else if (i == N) {
        offs[N] = E;
    }
}

// Atomic-free scatter: esrc[offs[d] + rank[e]] = src[e].
// NPASS dst-range passes confine the random-write window to ~E/NPASS*4 bytes so
// partial lines merge in L2 before HBM writeback. adj re-reads hit L3.
template <int NPASS>
__global__ __launch_bounds__(256) void scatter_nr_k(const int* __restrict__ src,
                                                    const int* __restrict__ dst,
                                                    const u16* __restrict__ rank,
                                                    const int* __restrict__ offs,
                                                    int* __restrict__ esrc, int E, int N) {
    const int stride = gridDim.x * 256;
    const int t0 = blockIdx.x * 256 + threadIdx.x;
    const int span = (N + NPASS - 1) / NPASS;
#pragma unroll 1
    for (int p = 0; p < NPASS; ++p) {
        const int lo = p * span, hi = lo + span;
        for (int e = t0; e < E; e += stride) {
            int d = dst[e];
            d = d < 0 ? 0 : (d >= N ? N - 1 : d);
            if (d >= lo && d < hi) {
                int s = src[e];
                s = s < 0 ? 0 : (s >= N ? N - 1 : s);
                esrc[offs[d] + (int)rank[e]] = s;
            }
        }
    }
}

// ---------------- weight prepack (fp32 -> bf16 MFMA-fragment order), all 3 layers ----------------
// Wf[(kq*DO + n)*8 + j] = bf16(W[(kq*8 + j)*DO + n])   (k = kq*8 + j)
__device__ __forceinline__ void prepack1(const float* W, u16* Wf, int DO, int idx) {
    int j = idx & 7;
    int t = idx >> 3;
    int n = t % DO;
    int kq = t / DO;
    Wf[idx] = f2bf(W[(size_t)(kq * 8 + j) * DO + n]);
}

__global__ void prepack3_k(const float* __restrict__ W1, u16* __restrict__ Wf1,
                           const float* __restrict__ W2, u16* __restrict__ Wf2,
                           const float* __restrict__ W3, u16* __restrict__ Wf3) {
    int idx = blockIdx.x * 256 + threadIdx.x;
    const int T1 = 512 * 128, T2 = 128 * 128, T3 = 128 * 64;
    if (idx < T1) prepack1(W1, Wf1, 128, idx);
    else if (idx < T1 + T2) prepack1(W2, Wf2, 128, idx - T1);
    else if (idx < T1 + T2 + T3) prepack1(W3, Wf3, 64, idx - T1 - T2);
}

// ---------------- GEMM + fused alpha dots ----------------
// H = X @ W (bf16 MFMA, fp32 acc); AS/AD = H . a_src/a_dst from fp32 accs.
// F32IN: X fp32 (convert during staging) else bf16. H32: store H fp32 else bf16.
template <int K, int DO, bool F32IN, bool H32>
__global__ __launch_bounds__(256, 2) void gemm_k(const void* __restrict__ Xv,
                                                 const u16* __restrict__ Wf,
                                                 void* __restrict__ Hv,
                                                 const float* __restrict__ a_src,
                                                 const float* __restrict__ a_dst,
                                                 float* __restrict__ AS,
                                                 float* __restrict__ AD, int nrow) {
    constexpr int BM = 128, BK = 64;
    __shared__ alignas(16) u16 At[BM * BK];  // 16 KB bf16, XOR-swizzled 16B units
    const int tid = threadIdx.x;
    const int wave = tid >> 6, lane = tid & 63;
    const int quad = lane >> 4, l16 = lane & 15;
    const int row0 = blockIdx.x * BM;

    floatx4 acc[2][DO / 16];
#pragma unroll
    for (int a = 0; a < 2; a++)
#pragma unroll
        for (int b = 0; b < DO / 16; b++) acc[a][b] = floatx4{0.f, 0.f, 0.f, 0.f};

    for (int kt = 0; kt < K / BK; ++kt) {
        __syncthreads();
#pragma unroll
        for (int i = 0; i < 4; ++i) {
            int seg = tid + i * 256;          // 1024 segments of 8 k-elements
            int r = seg >> 3, c = seg & 7;
            int gr = row0 + r;
            gr = gr < nrow ? gr : nrow - 1;   // clamp (pad rows discarded on store)
            u16 pk[8];
            if (F32IN) {
                const float* X = (const float*)Xv;
                float4 v0 = *(const float4*)(X + (size_t)gr * K + kt * BK + c * 8);
                float4 v1 = *(const float4*)(X + (size_t)gr * K + kt * BK + c * 8 + 4);
                pk[0] = f2bf(v0.x); pk[1] = f2bf(v0.y); pk[2] = f2bf(v0.z); pk[3] = f2bf(v0.w);
                pk[4] = f2bf(v1.x); pk[5] = f2bf(v1.y); pk[6] = f2bf(v1.z); pk[7] = f2bf(v1.w);
                *(int4*)(At + r * BK + (c ^ (r & 7)) * 8) = *(const int4*)pk;
            } else {
                const u16* X = (const u16*)Xv;
                int4 v = *(const int4*)(X + (size_t)gr * K + kt * BK + c * 8);
                *(int4*)(At + r * BK + (c ^ (r & 7)) * 8) = v;
            }
        }
        __syncthreads();
#pragma unroll
        for (int ks = 0; ks < 2; ++ks) {
            short8 bfr[DO / 16];
            int kq = kt * 8 + ks * 4 + quad;
#pragma unroll
            for (int ct = 0; ct < DO / 16; ++ct)
                bfr[ct] = *(const short8*)(Wf + ((size_t)kq * DO + ct * 16 + l16) * 8);
#pragma unroll
            for (int rt = 0; rt < 2; ++rt) {
                int row = wave * 32 + rt * 16 + l16;
                int unit = (ks * 4 + quad) ^ (row & 7);
                short8 afr = *(const short8*)(At + row * BK + unit * 8);
#pragma unroll
                for (int ct = 0; ct < DO / 16; ++ct)
                    acc[rt][ct] =
                        __builtin_amdgcn_mfma_f32_16x16x32_bf16(afr, bfr[ct], acc[rt][ct], 0, 0, 0);
            }
        }
    }
    // Epilogue. C/D layout: col = ct*16 + l16, row = quad*4 + r  [m89/m91 verified].
    // Fused alpha dots: partial over this lane's 8 (or 4) cols, reduce across l16 group.
    float asv[DO / 16], adv[DO / 16];
#pragma unroll
    for (int ct = 0; ct < DO / 16; ++ct) {
        asv[ct] = a_src[ct * 16 + l16];
        adv[ct] = a_dst[ct * 16 + l16];
    }
#pragma unroll
    for (int rt = 0; rt < 2; ++rt)
#pragma unroll
        for (int r = 0; r < 4; ++r) {
            int grow = row0 + wave * 32 + rt * 16 + quad * 4 + r;
            bool ok = grow < nrow;
            float ps = 0.f, pd = 0.f;
#pragma unroll
            for (int ct = 0; ct < DO / 16; ++ct) {
                float v = acc[rt][ct][r];
                ps = fmaf(v, asv[ct], ps);
                pd = fmaf(v, adv[ct], pd);
                if (ok) {
                    if (H32)
                        ((float*)Hv)[(size_t)grow * DO + ct * 16 + l16] = v;
                    else
                        ((u16*)Hv)[(size_t)grow * DO + ct * 16 + l16] = f2bf(v);
                }
            }
            // reduce over the 16-lane col group (xor bits 0-3 stay within quad)
#pragma unroll
            for (int o = 1; o < 16; o <<= 1) {
                ps += __shfl_xor(ps, o);
                pd += __shfl_xor(pd, o);
            }
            if (ok && l16 == 0) {
                AS[grow] = ps;
                AD[grow] = pd;
            }
        }
}

// ---------------- fused segment softmax + aggregate (one wave per dst node) ----------------
// Row layout is 256B in all configs (DO=128 bf16 or DO=64 fp32).
// Gather scheme: 16 lanes own one edge-row; a wave processes 4 edges per load
// instruction (dwordx4, 16B/lane). Accumulators are a 16B col-slice per lane;
// folded across the 4 edge-subsets at the end via shfl_xor(16/32).
// HB: h rows are bf16 (else fp32). OUTB: write bf16 packed (else fp32).
template <int DO, bool HB, bool OUTB>
__global__ __launch_bounds__(256) void agg_k(const void* __restrict__ Hv,
                                             const float* __restrict__ AS,
                                             const float* __restrict__ AD,
                                             const int* __restrict__ offs,
                                             const int* __restrict__ esrc,
                                             const float* __restrict__ bias,
                                             void* __restrict__ OUT, int N) {
    constexpr int NC = DO / 16;  // floats per lane: 8 (bf16x8) or 4 (fp32x4) = 16B slice
    const int wave = threadIdx.x >> 6, lane = threadIdx.x & 63;
    const int sub = lane >> 4, l16 = lane & 15;
    const int d = blockIdx.x * 4 + wave;
    if (d >= N) return;
    const int o0 = offs[d];
    const int deg = offs[d + 1] - o0;  // real in-edges
    const int tot = deg + 1;           // + self loop
    const float ad = AD[d];

    float acc[NC];
#pragma unroll
    for (int c = 0; c < NC; ++c) acc[c] = 0.f;

    // gather one row-slice (16B) of row sl with weight wl
    auto gath = [&](float wl, int sl) {
        if (HB) {
            uint4 hv = ((const uint4*)Hv)[(size_t)sl * 16 + l16];
            u32 p[4] = {hv.x, hv.y, hv.z, hv.w};
#pragma unroll
            for (int c = 0; c < 4; ++c) {
                acc[2 * c] = fmaf(wl, bf2f((u16)p[c]), acc[2 * c]);
                acc[2 * c + 1] = fmaf(wl, bf2f((u16)(p[c] >> 16)), acc[2 * c + 1]);
            }
        } else {
            float4 hv = ((const float4*)Hv)[(size_t)sl * 16 + l16];
            acc[0] = fmaf(wl, hv.x, acc[0]);
            acc[1] = fmaf(wl, hv.y, acc[1]);
            acc[2] = fmaf(wl, hv.z, acc[2]);
            acc[3] = fmaf(wl, hv.w, acc[3]);
        }
    };
    // 4 edges starting at l: sub-group `sub` takes edge l+sub (w,s live in lane idx)
    auto quad = [&](float w, int s, int l, int lim) {
        int idx = l + sub;
        int cl = idx < lim ? idx : lim - 1;
        float wv = __shfl(w, cl);  // ds_bpermute, per-lane src index
        int sl = __shfl(s, cl);
        gath(idx < lim ? wv : 0.f, sl);
    };

    if (tot <= 64) {
        // ---- fast path: whole segment resident in one wave, single gather pass ----
        int s = (lane < deg) ? esrc[o0 + lane] : d;  // lane==deg -> self loop
        bool valid = lane < tot;
        float lg = AS[s] + ad;
        lg = lg > 0.f ? lg : lg * 0.2f;
        float lgv = valid ? lg : -1e30f;
        float m = lgv;
        for (int o = 32; o; o >>= 1) m = fmaxf(m, __shfl_xor(m, o));
        float e = valid ? __expf(lg - m) : 0.f;
        float sum = e;
        for (int o = 32; o; o >>= 1) sum += __shfl_xor(sum, o);
        float w = e * (1.f / sum);
        // 16 edges (4 groups of 4) in flight per iteration
        for (int l = 0; l < tot; l += 16) {
#pragma unroll
            for (int g = 0; g < 4; ++g)
                if (l + g * 4 < tot) quad(w, s, l + g * 4, tot);
        }
    } else {
        // ---- general path (deg > 63, vanishingly rare at avg deg 16): 3-pass ----
        float mx = -1e30f;
        for (int i = lane; i < tot; i += 64) {
            int s = (i < deg) ? esrc[o0 + i] : d;
            float lg = AS[s] + ad;
            lg = lg > 0.f ? lg : lg * 0.2f;
            mx = fmaxf(mx, lg);
        }
        for (int o = 32; o; o >>= 1) mx = fmaxf(mx, __shfl_xor(mx, o));
        float sum = 0.f;
        for (int i = lane; i < tot; i += 64) {
            int s = (i < deg) ? esrc[o0 + i] : d;
            float lg = AS[s] + ad;
            lg = lg > 0.f ? lg : lg * 0.2f;
            sum += __expf(lg - mx);
        }
        for (int o = 32; o; o >>= 1) sum += __shfl_xor(sum, o);
        const float inv = 1.f / sum;
        for (int c0 = 0; c0 < tot; c0 += 64) {
            int i = c0 + lane;
            float w = 0.f;
            int s = d;
            if (i < tot) {
                s = (i < deg) ? esrc[o0 + i] : d;
                float lg = AS[s] + ad;
                lg = lg > 0.f ? lg : lg * 0.2f;
                w = __expf(lg - mx) * inv;
            }
            int cn = tot - c0;
            cn = cn < 64 ? cn : 64;
            for (int l = 0; l < cn; l += 16) {
#pragma unroll
                for (int g = 0; g < 4; ++g)
                    if (l + g * 4 < cn) quad(w, s, l + g * 4, cn);
            }
        }
    }

    // fold the 4 edge-subsets: lanes (sub,l16) all end with full sum for their slice
#pragma unroll
    for (int c = 0; c < NC; ++c) {
        acc[c] += __shfl_xor(acc[c], 16);
        acc[c] += __shfl_xor(acc[c], 32);
    }

    // epilogue: + bias, leaky_relu(0.25), store (sub==0 lanes write 16B each)
    if (sub == 0) {
        if (DO == 128) {
            u32 pk[4];
            float fv[8];
#pragma unroll
            for (int c = 0; c < 8; ++c) {
                float v = acc[c] + bias[l16 * 8 + c];
                fv[c] = v > 0.f ? v : v * 0.25f;
            }
            if (OUTB) {
#pragma unroll
                for (int c = 0; c < 4; ++c)
                    pk[c] = (u32)f2bf(fv[2 * c]) | ((u32)f2bf(fv[2 * c + 1]) << 16);
                ((uint4*)OUT)[(size_t)d * 16 + l16] = uint4{pk[0], pk[1], pk[2], pk[3]};
            } else {
                float4 o0v = float4{fv[0], fv[1], fv[2], fv[3]};
                float4 o1v = float4{fv[4], fv[5], fv[6], fv[7]};
                ((float4*)OUT)[(size_t)d * 32 + l16 * 2] = o0v;
                ((float4*)OUT)[(size_t)d * 32 + l16 * 2 + 1] = o1v;
            }
        } else {
            float4 v;
            v.x = acc[0] + bias[l16 * 4 + 0];
            v.y = acc[1] + bias[l16 * 4 + 1];
            v.z = acc[2] + bias[l16 * 4 + 2];
            v.w = acc[3] + bias[l16 * 4 + 3];
            v.x = v.x > 0.f ? v.x : v.x * 0.25f;
            v.y = v.y > 0.f ? v.y : v.y * 0.25f;
            v.z = v.z > 0.f ? v.z : v.z * 0.25f;
            v.w = v.w > 0.f ? v.w : v.w * 0.25f;
            if (OUTB) {
                u32 p0 = (u32)f2bf(v.x) | ((u32)f2bf(v.y) << 16);
                u32 p1 = (u32)f2bf(v.z) | ((u32)f2bf(v.w) << 16);
                ((uint2*)OUT)[(size_t)d * 16 + l16] = uint2{p0, p1};
            } else {
                ((float4*)OUT)[(size_t)d * 16 + l16] = v;
            }
        }
    }
}

// ---------------- launch ----------------

extern "C" void kernel_launch(void* const* d_in, const int* in_sizes, int n_in,
                              void* d_out, int out_size, void* d_ws, size_t ws_size,
                              hipStream_t stream) {
    const int N = in_sizes[0] / 512;  // 100000
    const int E = in_sizes[1] / 2;    // 1600000

    const float* data = (const float*)d_in[0];
    const int* adj = (const int*)d_in[1];
    const float* W1 = (const float*)d_in[2];
    const float* as1 = (const float*)d_in[3];
    const float* ad1 = (const float*)d_in[4];
    const float* b1 = (const float*)d_in[5];
    const float* W2 = (const float*)d_in[6];
    const float* as2 = (const float*)d_in[7];
    const float* ad2 = (const float*)d_in[8];
    const float* b2 = (const float*)d_in[9];
    const float* W3 = (const float*)d_in[10];
    const float* as3 = (const float*)d_in[11];
    const float* ad3 = (const float*)d_in[12];
    const float* b3 = (const float*)d_in[13];

    // ---- workspace carve + budget check ----
    char* ws = (char*)d_ws;
    size_t need = 0;
    auto carve = [&](size_t bytes) {
        void* p = (void*)(ws + need);
        need += (bytes + 255) & ~(size_t)255;
        return p;
    };
    int* esrc = (int*)carve((size_t)E * 4);
    int* offs = (int*)carve((size_t)(N + 1) * 4);
    int* cnt = (int*)carve((size_t)N * 4);
    int* excl = (int*)carve((size_t)N * 4);
    int* aux = (int*)carve(1024);
    float* AS = (float*)carve((size_t)N * 4);
    float* AD = (float*)carve((size_t)N * 4);
    u16* Hb = (u16*)carve((size_t)N * 128 * 2);  // bf16 h (layers 1-2)
    float* H32 = (float*)Hb;                     // fp32 h for layer 3 (DO=64): same 25.6 MB
    u16* x1 = (u16*)carve((size_t)N * 128 * 2);  // bf16 next-layer input
    u16* x2 = x1;                                // x1 dead after layer-2 GEMM
    u16* Wf1 = (u16*)carve(512 * 128 * 2);
    u16* Wf2 = (u16*)carve(128 * 128 * 2);
    u16* Wf3 = (u16*)carve(128 * 64 * 2);

    // rank lives in Hb: written by hist, consumed by scatter, both before gemm1 writes Hb
    u16* rank = (u16*)Hb;

    if (need > ws_size) {
        // Diagnostic signature: absmax == ref absmax (0.2373) => ws too small.
        zero_out_k<<<(out_size + 255) / 256, 256, 0, stream>>>((float*)d_out, out_size);
        return;
    }

    const int* srcl = adj;
    const int* dstl = adj + E;

    // ---- CSR build (once, reused by all 3 layers) ----
    hipMemsetAsync(cnt, 0, (size_t)N * 4, stream);
    hist_rank_k<<<(E + 255) / 256, 256, 0, stream>>>(dstl, cnt, rank, E, N);
    int nb = (N + 1023) / 1024;
    scan1_k<<<nb, 1024, 0, stream>>>(cnt, excl, aux, N);
    scan2_k<<<1, 64, 0, stream>>>(aux, nb);
    scan3_k<<<nb, 1024, 0, stream>>>(excl, aux, offs, N, E);
    scatter_nr_k<8><<<2048, 256, 0, stream>>>(srcl, dstl, rank, offs, esrc, E, N);

    // ---- weight prepack (fp32 -> bf16 fragments), single launch ----
    {
        const int total = 512 * 128 + 128 * 128 + 128 * 64;
        prepack3_k<<<(total + 255) / 256, 256, 0, stream>>>(W1, Wf1, W2, Wf2, W3, Wf3);
    }

    const int gblk = (N + 127) / 128;
    const int nblk = (N + 3) / 4;

    // ---- layer 1 ----
    gemm_k<512, 128, true, false><<<gblk, 256, 0, stream>>>(data, Wf1, Hb, as1, ad1, AS, AD, N);
    agg_k<128, true, true><<<nblk, 256, 0, stream>>>(Hb, AS, AD, offs, esrc, b1, x1, N);
    // ---- layer 2 ----
    gemm_k<128, 128, false, false><<<gblk, 256, 0, stream>>>(x1, Wf2, Hb, as2, ad2, AS, AD, N);
    agg_k<128, true, true><<<nblk, 256, 0, stream>>>(Hb, AS, AD, offs, esrc, b2, x2, N);
    // ---- layer 3 (fp32 h for final accuracy; 256 B/row gather either way) ----
    gemm_k<128, 64, false, true><<<gblk, 256, 0, stream>>>(x2, Wf3, H32, as3, ad3, AS, AD, N);
    agg_k<64, false, false><<<nblk, 256, 0, stream>>>(H32, AS, AD, offs, esrc, b3, d_out, N);
}

// Round 3
// 672.330 us; speedup vs baseline: 1.3543x; 1.0199x over previous
//
#include <hip/hip_runtime.h>

typedef unsigned short u16;
typedef unsigned int u32;
typedef short short8 __attribute__((ext_vector_type(8)));
typedef float floatx4 __attribute__((ext_vector_type(4)));

__device__ __forceinline__ float bf2f(u16 x) { return __uint_as_float(((u32)x) << 16); }
__device__ __forceinline__ u16 f2bf(float x) {
    u32 u = __float_as_uint(x);
    u += 0x7fffu + ((u >> 16) & 1u);
    return (u16)(u >> 16);
}
// pack two fp32 -> u32 of 2 bf16 (RNE), single HW instruction
__device__ __forceinline__ u32 cvt_pk_bf16(float lo, float hi) {
    u32 r;
    asm("v_cvt_pk_bf16_f32 %0, %1, %2" : "=v"(r) : "v"(lo), "v"(hi));
    return r;
}

// ---------------- diagnostic: zero the output (fp32) ----------------
__global__ void zero_out_k(float* __restrict__ out, int n) {
    int i = blockIdx.x * 256 + threadIdx.x;
    if (i < n) out[i] = 0.f;
}

// ---------------- CSR build: histogram+rank (+weight prepack piggyback) ----------------

// Wf[(kq*DO + n)*8 + j] = bf16(W[(kq*8 + j)*DO + n])   (k = kq*8 + j)
__device__ __forceinline__ void prepack1(const float* W, u16* Wf, int DO, int idx) {
    int j = idx & 7;
    int t = idx >> 3;
    int n = t % DO;
    int kq = t / DO;
    Wf[idx] = f2bf(W[(size_t)(kq * 8 + j) * DO + n]);
}

// rank[e] = position of edge e within its dst segment (u16: max degree ~60 here).
// First blocks also prepack the 3 weight matrices (independent work, saves a launch).
__global__ void hist_prepack_k(const int* __restrict__ dst, int* __restrict__ cnt,
                               u16* __restrict__ rank, int E, int N,
                               const float* __restrict__ W1, u16* __restrict__ Wf1,
                               const float* __restrict__ W2, u16* __restrict__ Wf2,
                               const float* __restrict__ W3, u16* __restrict__ Wf3) {
    int e = blockIdx.x * 256 + threadIdx.x;
    if (e < E) {
        int d = dst[e];
        d = d < 0 ? 0 : (d >= N ? N - 1 : d);
        rank[e] = (u16)atomicAdd(&cnt[d], 1);
    }
    const int T1 = 512 * 128, T2 = 128 * 128, T3 = 128 * 64;
    if (e < T1) prepack1(W1, Wf1, 128, e);
    else if (e < T1 + T2) prepack1(W2, Wf2, 128, e - T1);
    else if (e < T1 + T2 + T3) prepack1(W3, Wf3, 64, e - T1 - T2);
}

// block-level exclusive scan: 16 waves, shfl-scan per wave + cross-wave LDS combine
__global__ void scan1_k(const int* __restrict__ cnt, int* __restrict__ excl,
                        int* __restrict__ aux, int N) {
    __shared__ int wsum[16];
    int t = threadIdx.x;
    int wv = t >> 6, ln = t & 63;
    int i = blockIdx.x * 1024 + t;
    int v = (i < N) ? cnt[i] : 0;
    int s = v;
    for (int off = 1; off < 64; off <<= 1) { int x = __shfl_up(s, off); if (ln >= off) s += x; }
    if (ln == 63) wsum[wv] = s;
    __syncthreads();
    if (wv == 0) {
        int ws = (ln < 16) ? wsum[ln] : 0;
        int ss = ws;
        for (int off = 1; off < 16; off <<= 1) { int x = __shfl_up(ss, off); if (ln >= off) ss += x; }
        if (ln < 16) wsum[ln] = ss - ws;  // exclusive wave offsets
    }
    __syncthreads();
    int base = wsum[wv];
    if (i < N) excl[i] = base + s - v;
    if (t == 1023) aux[blockIdx.x] = base + s;
}

__global__ void scan2_k(int* __restrict__ aux, int nb) {
    int lane = threadIdx.x;  // single block of 64; nb <= 128
    int v0 = (lane < nb) ? aux[lane] : 0;
    int v1 = (lane + 64 < nb) ? aux[lane + 64] : 0;
    int s0 = v0;
    for (int off = 1; off < 64; off <<= 1) { int x = __shfl_up(s0, off); if (lane >= off) s0 += x; }
    int total0 = __shfl(s0, 63);
    int s1 = v1;
    for (int off = 1; off < 64; off <<= 1) { int x = __shfl_up(s1, off); if (lane >= off) s1 += x; }
    if (lane < nb) aux[lane] = s0 - v0;
    if (lane + 64 < nb) aux[lane + 64] = total0 + s1 - v1;
}

__global__ void scan3_k(const int* __restrict__ excl, const int* __restrict__ aux,
                        int* __restrict__ offs, int N, int E) {
    int i = blockIdx.x * 1024 + threadIdx.x;
    if (i < N) {
        offs[i] = excl[i] + aux[blockIdx.x];
    } else if (i == N) {
        offs[N] = E;
    }
}

// Atomic-free scatter: esrc[offs[d] + rank[e]] = src[e].
// NPASS dst-range passes confine the random-write window so partial lines merge
// in L2 before HBM writeback. adj re-reads hit L3.
template <int NPASS>
__global__ __launch_bounds__(256) void scatter_nr_k(const int* __restrict__ src,
                                                    const int* __restrict__ dst,
                                                    const u16* __restrict__ rank,
                                                    const int* __restrict__ offs,
                                                    int* __restrict__ esrc, int E, int N) {
    const int stride = gridDim.x * 256;
    const int t0 = blockIdx.x * 256 + threadIdx.x;
    const int span = (N + NPASS - 1) / NPASS;
#pragma unroll 1
    for (int p = 0; p < NPASS; ++p) {
        const int lo = p * span, hi = lo + span;
        for (int e = t0; e < E; e += stride) {
            int d = dst[e];
            d = d < 0 ? 0 : (d >= N ? N - 1 : d);
            if (d >= lo && d < hi) {
                int s = src[e];
                s = s < 0 ? 0 : (s >= N ? N - 1 : s);
                esrc[offs[d] + (int)rank[e]] = s;
            }
        }
    }
}

// ---------------- GEMM + fused alpha dots ----------------
// H = X @ W (bf16 MFMA, fp32 acc); AS/AD = H . a_src/a_dst from fp32 accs.
// F32IN: X fp32 (convert during staging) else bf16. H32: store H fp32 else bf16.
template <int K, int DO, bool F32IN, bool H32>
__global__ __launch_bounds__(256, 2) void gemm_k(const void* __restrict__ Xv,
                                                 const u16* __restrict__ Wf,
                                                 void* __restrict__ Hv,
                                                 const float* __restrict__ a_src,
                                                 const float* __restrict__ a_dst,
                                                 float* __restrict__ AS,
                                                 float* __restrict__ AD, int nrow) {
    constexpr int BM = 128, BK = 64;
    __shared__ alignas(16) u16 At[BM * BK];  // 16 KB bf16, XOR-swizzled 16B units
    const int tid = threadIdx.x;
    const int wave = tid >> 6, lane = tid & 63;
    const int quad = lane >> 4, l16 = lane & 15;
    const int row0 = blockIdx.x * BM;

    floatx4 acc[2][DO / 16];
#pragma unroll
    for (int a = 0; a < 2; a++)
#pragma unroll
        for (int b = 0; b < DO / 16; b++) acc[a][b] = floatx4{0.f, 0.f, 0.f, 0.f};

    for (int kt = 0; kt < K / BK; ++kt) {
        __syncthreads();
#pragma unroll
        for (int i = 0; i < 4; ++i) {
            int seg = tid + i * 256;          // 1024 segments of 8 k-elements
            int r = seg >> 3, c = seg & 7;
            int gr = row0 + r;
            gr = gr < nrow ? gr : nrow - 1;   // clamp (pad rows discarded on store)
            if (F32IN) {
                const float* X = (const float*)Xv;
                float4 v0 = *(const float4*)(X + (size_t)gr * K + kt * BK + c * 8);
                float4 v1 = *(const float4*)(X + (size_t)gr * K + kt * BK + c * 8 + 4);
                int4 pk;
                pk.x = (int)cvt_pk_bf16(v0.x, v0.y);
                pk.y = (int)cvt_pk_bf16(v0.z, v0.w);
                pk.z = (int)cvt_pk_bf16(v1.x, v1.y);
                pk.w = (int)cvt_pk_bf16(v1.z, v1.w);
                *(int4*)(At + r * BK + (c ^ (r & 7)) * 8) = pk;
            } else {
                const u16* X = (const u16*)Xv;
                int4 v = *(const int4*)(X + (size_t)gr * K + kt * BK + c * 8);
                *(int4*)(At + r * BK + (c ^ (r & 7)) * 8) = v;
            }
        }
        __syncthreads();
#pragma unroll
        for (int ks = 0; ks < 2; ++ks) {
            short8 bfr[DO / 16];
            int kq = kt * 8 + ks * 4 + quad;
#pragma unroll
            for (int ct = 0; ct < DO / 16; ++ct)
                bfr[ct] = *(const short8*)(Wf + ((size_t)kq * DO + ct * 16 + l16) * 8);
#pragma unroll
            for (int rt = 0; rt < 2; ++rt) {
                int row = wave * 32 + rt * 16 + l16;
                int unit = (ks * 4 + quad) ^ (row & 7);
                short8 afr = *(const short8*)(At + row * BK + unit * 8);
#pragma unroll
                for (int ct = 0; ct < DO / 16; ++ct)
                    acc[rt][ct] =
                        __builtin_amdgcn_mfma_f32_16x16x32_bf16(afr, bfr[ct], acc[rt][ct], 0, 0, 0);
            }
        }
    }
    // Epilogue. C/D layout: col = ct*16 + l16, row = quad*4 + r  [m89/m91 verified].
    // Fused alpha dots: partial over this lane's cols, reduce across l16 group.
    float asv[DO / 16], adv[DO / 16];
#pragma unroll
    for (int ct = 0; ct < DO / 16; ++ct) {
        asv[ct] = a_src[ct * 16 + l16];
        adv[ct] = a_dst[ct * 16 + l16];
    }
#pragma unroll
    for (int rt = 0; rt < 2; ++rt)
#pragma unroll
        for (int r = 0; r < 4; ++r) {
            int grow = row0 + wave * 32 + rt * 16 + quad * 4 + r;
            bool ok = grow < nrow;
            float ps = 0.f, pd = 0.f;
#pragma unroll
            for (int ct = 0; ct < DO / 16; ++ct) {
                float v = acc[rt][ct][r];
                ps = fmaf(v, asv[ct], ps);
                pd = fmaf(v, adv[ct], pd);
                if (ok) {
                    if (H32)
                        ((float*)Hv)[(size_t)grow * DO + ct * 16 + l16] = v;
                    else
                        ((u16*)Hv)[(size_t)grow * DO + ct * 16 + l16] = f2bf(v);
                }
            }
            // reduce over the 16-lane col group (xor bits 0-3 stay within quad)
#pragma unroll
            for (int o = 1; o < 16; o <<= 1) {
                ps += __shfl_xor(ps, o);
                pd += __shfl_xor(pd, o);
            }
            if (ok && l16 == 0) {
                AS[grow] = ps;
                AD[grow] = pd;
            }
        }
}

// ---------------- fused segment softmax + aggregate (one wave per dst node) ----------------
// Gather scheme: 16 lanes own one edge-row; a wave processes 4 edges per load
// instruction. Row = 256B (DO=128 bf16 / DO=64 fp32) or 128B (DO=64 bf16).
// Accumulators are a row-slice per lane; folded across the 4 edge-subsets via
// shfl_xor(16/32). HB: h rows bf16 (else fp32). OUTB: write bf16 packed (else fp32).
template <int DO, bool HB, bool OUTB>
__global__ __launch_bounds__(256) void agg_k(const void* __restrict__ Hv,
                                             const float* __restrict__ AS,
                                             const float* __restrict__ AD,
                                             const int* __restrict__ offs,
                                             const int* __restrict__ esrc,
                                             const float* __restrict__ bias,
                                             void* __restrict__ OUT, int N) {
    constexpr int NC = HB ? DO / 16 : 4;  // floats per lane slice (bf16: DO/16, fp32: 4)
    const int wave = threadIdx.x >> 6, lane = threadIdx.x & 63;
    const int sub = lane >> 4, l16 = lane & 15;
    const int d = blockIdx.x * 4 + wave;
    if (d >= N) return;
    const int o0 = offs[d];
    const int deg = offs[d + 1] - o0;  // real in-edges
    const int tot = deg + 1;           // + self loop
    const float ad = AD[d];

    float acc[NC];
#pragma unroll
    for (int c = 0; c < NC; ++c) acc[c] = 0.f;

    // gather one row-slice of row sl with weight wl
    auto gath = [&](float wl, int sl) {
        if (HB) {
            if (DO == 128) {
                // 256B row: lane slice = uint4 (8 bf16)
                uint4 hv = ((const uint4*)Hv)[(size_t)sl * 16 + l16];
                u32 p[4] = {hv.x, hv.y, hv.z, hv.w};
#pragma unroll
                for (int c = 0; c < 4; ++c) {
                    acc[2 * c] = fmaf(wl, bf2f((u16)p[c]), acc[2 * c]);
                    acc[2 * c + 1] = fmaf(wl, bf2f((u16)(p[c] >> 16)), acc[2 * c + 1]);
                }
            } else {
                // 128B row: lane slice = uint2 (4 bf16)
                uint2 hv = ((const uint2*)Hv)[(size_t)sl * 16 + l16];
                acc[0] = fmaf(wl, bf2f((u16)hv.x), acc[0]);
                acc[1] = fmaf(wl, bf2f((u16)(hv.x >> 16)), acc[1]);
                acc[2] = fmaf(wl, bf2f((u16)hv.y), acc[2]);
                acc[3] = fmaf(wl, bf2f((u16)(hv.y >> 16)), acc[3]);
            }
        } else {
            float4 hv = ((const float4*)Hv)[(size_t)sl * 16 + l16];
            acc[0] = fmaf(wl, hv.x, acc[0]);
            acc[1] = fmaf(wl, hv.y, acc[1]);
            acc[2] = fmaf(wl, hv.z, acc[2]);
            acc[3] = fmaf(wl, hv.w, acc[3]);
        }
    };
    // 4 edges starting at l: sub-group `sub` takes edge l+sub (w,s live in lane idx)
    auto quad = [&](float w, int s, int l, int lim) {
        int idx = l + sub;
        int cl = idx < lim ? idx : lim - 1;
        float wv = __shfl(w, cl);  // ds_bpermute, per-lane src index
        int sl = __shfl(s, cl);
        gath(idx < lim ? wv : 0.f, sl);
    };

    if (tot <= 64) {
        // ---- fast path: whole segment resident in one wave, single gather pass ----
        int s = (lane < deg) ? esrc[o0 + lane] : d;  // lane==deg -> self loop
        bool valid = lane < tot;
        float lg = AS[s] + ad;
        lg = lg > 0.f ? lg : lg * 0.2f;
        float lgv = valid ? lg : -1e30f;
        float m = lgv;
        for (int o = 32; o; o >>= 1) m = fmaxf(m, __shfl_xor(m, o));
        float e = valid ? __expf(lg - m) : 0.f;
        float sum = e;
        for (int o = 32; o; o >>= 1) sum += __shfl_xor(sum, o);
        float w = e * (1.f / sum);
        // 16 edges (4 groups of 4) in flight per iteration
        for (int l = 0; l < tot; l += 16) {
#pragma unroll
            for (int g = 0; g < 4; ++g)
                if (l + g * 4 < tot) quad(w, s, l + g * 4, tot);
        }
    } else {
        // ---- general path (deg > 63, rare at avg deg 16): 3-pass ----
        float mx = -1e30f;
        for (int i = lane; i < tot; i += 64) {
            int s = (i < deg) ? esrc[o0 + i] : d;
            float lg = AS[s] + ad;
            lg = lg > 0.f ? lg : lg * 0.2f;
            mx = fmaxf(mx, lg);
        }
        for (int o = 32; o; o >>= 1) mx = fmaxf(mx, __shfl_xor(mx, o));
        float sum = 0.f;
        for (int i = lane; i < tot; i += 64) {
            int s = (i < deg) ? esrc[o0 + i] : d;
            float lg = AS[s] + ad;
            lg = lg > 0.f ? lg : lg * 0.2f;
            sum += __expf(lg - mx);
        }
        for (int o = 32; o; o >>= 1) sum += __shfl_xor(sum, o);
        const float inv = 1.f / sum;
        for (int c0 = 0; c0 < tot; c0 += 64) {
            int i = c0 + lane;
            float w = 0.f;
            int s = d;
            if (i < tot) {
                s = (i < deg) ? esrc[o0 + i] : d;
                float lg = AS[s] + ad;
                lg = lg > 0.f ? lg : lg * 0.2f;
                w = __expf(lg - mx) * inv;
            }
            int cn = tot - c0;
            cn = cn < 64 ? cn : 64;
            for (int l = 0; l < cn; l += 16) {
#pragma unroll
                for (int g = 0; g < 4; ++g)
                    if (l + g * 4 < cn) quad(w, s, l + g * 4, cn);
            }
        }
    }

    // fold the 4 edge-subsets: lanes (sub,l16) all end with full sum for their slice
#pragma unroll
    for (int c = 0; c < NC; ++c) {
        acc[c] += __shfl_xor(acc[c], 16);
        acc[c] += __shfl_xor(acc[c], 32);
    }

    // epilogue: + bias, leaky_relu(0.25), store (sub==0 lanes write their slice)
    if (sub == 0) {
        if (DO == 128) {
            u32 pk[4];
            float fv[8];
#pragma unroll
            for (int c = 0; c < 8; ++c) {
                float v = acc[c] + bias[l16 * 8 + c];
                fv[c] = v > 0.f ? v : v * 0.25f;
            }
            if (OUTB) {
#pragma unroll
                for (int c = 0; c < 4; ++c)
                    pk[c] = (u32)f2bf(fv[2 * c]) | ((u32)f2bf(fv[2 * c + 1]) << 16);
                ((uint4*)OUT)[(size_t)d * 16 + l16] = uint4{pk[0], pk[1], pk[2], pk[3]};
            } else {
                float4 o0v = float4{fv[0], fv[1], fv[2], fv[3]};
                float4 o1v = float4{fv[4], fv[5], fv[6], fv[7]};
                ((float4*)OUT)[(size_t)d * 32 + l16 * 2] = o0v;
                ((float4*)OUT)[(size_t)d * 32 + l16 * 2 + 1] = o1v;
            }
        } else {
            // DO=64: lane slice = cols l16*4..+3 (both HB and fp32 paths)
            float4 v;
            v.x = acc[0] + bias[l16 * 4 + 0];
            v.y = acc[1] + bias[l16 * 4 + 1];
            v.z = acc[2] + bias[l16 * 4 + 2];
            v.w = acc[3] + bias[l16 * 4 + 3];
            v.x = v.x > 0.f ? v.x : v.x * 0.25f;
            v.y = v.y > 0.f ? v.y : v.y * 0.25f;
            v.z = v.z > 0.f ? v.z : v.z * 0.25f;
            v.w = v.w > 0.f ? v.w : v.w * 0.25f;
            if (OUTB) {
                u32 p0 = (u32)f2bf(v.x) | ((u32)f2bf(v.y) << 16);
                u32 p1 = (u32)f2bf(v.z) | ((u32)f2bf(v.w) << 16);
                ((uint2*)OUT)[(size_t)d * 16 + l16] = uint2{p0, p1};
            } else {
                ((float4*)OUT)[(size_t)d * 16 + l16] = v;
            }
        }
    }
}

// ---------------- launch ----------------

extern "C" void kernel_launch(void* const* d_in, const int* in_sizes, int n_in,
                              void* d_out, int out_size, void* d_ws, size_t ws_size,
                              hipStream_t stream) {
    const int N = in_sizes[0] / 512;  // 100000
    const int E = in_sizes[1] / 2;    // 1600000

    const float* data = (const float*)d_in[0];
    const int* adj = (const int*)d_in[1];
    const float* W1 = (const float*)d_in[2];
    const float* as1 = (const float*)d_in[3];
    const float* ad1 = (const float*)d_in[4];
    const float* b1 = (const float*)d_in[5];
    const float* W2 = (const float*)d_in[6];
    const float* as2 = (const float*)d_in[7];
    const float* ad2 = (const float*)d_in[8];
    const float* b2 = (const float*)d_in[9];
    const float* W3 = (const float*)d_in[10];
    const float* as3 = (const float*)d_in[11];
    const float* ad3 = (const float*)d_in[12];
    const float* b3 = (const float*)d_in[13];

    // ---- workspace carve + budget check ----
    char* ws = (char*)d_ws;
    size_t need = 0;
    auto carve = [&](size_t bytes) {
        void* p = (void*)(ws + need);
        need += (bytes + 255) & ~(size_t)255;
        return p;
    };
    int* esrc = (int*)carve((size_t)E * 4);
    int* offs = (int*)carve((size_t)(N + 1) * 4);
    int* cnt = (int*)carve((size_t)N * 4);
    int* excl = (int*)carve((size_t)N * 4);
    int* aux = (int*)carve(1024);
    float* AS = (float*)carve((size_t)N * 4);
    float* AD = (float*)carve((size_t)N * 4);
    u16* Hb = (u16*)carve((size_t)N * 128 * 2);  // bf16 h (all 3 layers; L3 uses 64 cols)
    u16* x1 = (u16*)carve((size_t)N * 128 * 2);  // bf16 next-layer input
    u16* x2 = x1;                                // x1 dead after layer-2 GEMM
    u16* Wf1 = (u16*)carve(512 * 128 * 2);
    u16* Wf2 = (u16*)carve(128 * 128 * 2);
    u16* Wf3 = (u16*)carve(128 * 64 * 2);

    // rank lives in Hb: written by hist, consumed by scatter, both before gemm1 writes Hb
    u16* rank = (u16*)Hb;

    if (need > ws_size) {
        // Diagnostic signature: absmax == ref absmax (0.2373) => ws too small.
        zero_out_k<<<(out_size + 255) / 256, 256, 0, stream>>>((float*)d_out, out_size);
        return;
    }

    const int* srcl = adj;
    const int* dstl = adj + E;

    // ---- CSR build (once, reused by all 3 layers) + weight prepack piggyback ----
    hipMemsetAsync(cnt, 0, (size_t)N * 4, stream);
    hist_prepack_k<<<(E + 255) / 256, 256, 0, stream>>>(dstl, cnt, rank, E, N,
                                                        W1, Wf1, W2, Wf2, W3, Wf3);
    int nb = (N + 1023) / 1024;
    scan1_k<<<nb, 1024, 0, stream>>>(cnt, excl, aux, N);
    scan2_k<<<1, 64, 0, stream>>>(aux, nb);
    scan3_k<<<nb, 1024, 0, stream>>>(excl, aux, offs, N, E);
    scatter_nr_k<8><<<2048, 256, 0, stream>>>(srcl, dstl, rank, offs, esrc, E, N);

    const int gblk = (N + 127) / 128;
    const int nblk = (N + 3) / 4;

    // ---- layer 1 ----
    gemm_k<512, 128, true, false><<<gblk, 256, 0, stream>>>(data, Wf1, Hb, as1, ad1, AS, AD, N);
    agg_k<128, true, true><<<nblk, 256, 0, stream>>>(Hb, AS, AD, offs, esrc, b1, x1, N);
    // ---- layer 2 ----
    gemm_k<128, 128, false, false><<<gblk, 256, 0, stream>>>(x1, Wf2, Hb, as2, ad2, AS, AD, N);
    agg_k<128, true, true><<<nblk, 256, 0, stream>>>(Hb, AS, AD, offs, esrc, b2, x2, N);
    // ---- layer 3: h3 bf16 (128B rows) halves the agg3 gather volume ----
    gemm_k<128, 64, false, false><<<gblk, 256, 0, stream>>>(x2, Wf3, Hb, as3, ad3, AS, AD, N);
    agg_k<64, true, false><<<nblk, 256, 0, stream>>>(Hb, AS, AD, offs, esrc, b3, d_out, N);
}

// Round 4
// 655.451 us; speedup vs baseline: 1.3892x; 1.0258x over previous
//
#include <hip/hip_runtime.h>

typedef unsigned short u16;
typedef unsigned int u32;
typedef short short8 __attribute__((ext_vector_type(8)));
typedef float floatx4 __attribute__((ext_vector_type(4)));

__device__ __forceinline__ float bf2f(u16 x) { return __uint_as_float(((u32)x) << 16); }
__device__ __forceinline__ u16 f2bf(float x) {
    u32 u = __float_as_uint(x);
    u += 0x7fffu + ((u >> 16) & 1u);
    return (u16)(u >> 16);
}
// pack two fp32 -> u32 of 2 bf16 (RNE), single HW instruction
__device__ __forceinline__ u32 cvt_pk_bf16(float lo, float hi) {
    u32 r;
    asm("v_cvt_pk_bf16_f32 %0, %1, %2" : "=v"(r) : "v"(lo), "v"(hi));
    return r;
}

// ---------------- diagnostic: zero the output (fp32) ----------------
__global__ void zero_out_k(float* __restrict__ out, int n) {
    int i = blockIdx.x * 256 + threadIdx.x;
    if (i < n) out[i] = 0.f;
}

// ---------------- weight prepack helper ----------------
// Wf[(kq*DO + n)*8 + j] = bf16(W[(kq*8 + j)*DO + n])   (k = kq*8 + j)
__device__ __forceinline__ void prepack1(const float* W, u16* Wf, int DO, int idx) {
    int j = idx & 7;
    int t = idx >> 3;
    int n = t % DO;
    int kq = t / DO;
    Wf[idx] = f2bf(W[(size_t)(kq * 8 + j) * DO + n]);
}

// W1 prepack alone (must precede the fused kernel: gemm1 reads Wf1)
__global__ void prepack_w1_k(const float* __restrict__ W1, u16* __restrict__ Wf1) {
    int idx = blockIdx.x * 256 + threadIdx.x;
    if (idx < 512 * 128) prepack1(W1, Wf1, 128, idx);
}

// ---------------- GEMM body (shared by fused layer-1 kernel and standalone) ----------------
// H = X @ W (bf16 MFMA, fp32 acc); AS/AD = H . a_src/a_dst from fp32 accs.
// F32IN: X fp32 (convert during staging) else bf16.
template <int K, int DO, bool F32IN>
__device__ __forceinline__ void gemm_body(const void* __restrict__ Xv,
                                          const u16* __restrict__ Wf,
                                          void* __restrict__ Hv,
                                          const float* __restrict__ a_src,
                                          const float* __restrict__ a_dst,
                                          float* __restrict__ AS,
                                          float* __restrict__ AD, int nrow, int bid) {
    constexpr int BM = 128, BK = 64;
    __shared__ alignas(16) u16 At[BM * BK];  // 16 KB bf16, XOR-swizzled 16B units
    const int tid = threadIdx.x;
    const int wave = tid >> 6, lane = tid & 63;
    const int quad = lane >> 4, l16 = lane & 15;
    const int row0 = bid * BM;

    floatx4 acc[2][DO / 16];
#pragma unroll
    for (int a = 0; a < 2; a++)
#pragma unroll
        for (int b = 0; b < DO / 16; b++) acc[a][b] = floatx4{0.f, 0.f, 0.f, 0.f};

    for (int kt = 0; kt < K / BK; ++kt) {
        __syncthreads();
#pragma unroll
        for (int i = 0; i < 4; ++i) {
            int seg = tid + i * 256;          // 1024 segments of 8 k-elements
            int r = seg >> 3, c = seg & 7;
            int gr = row0 + r;
            gr = gr < nrow ? gr : nrow - 1;   // clamp (pad rows discarded on store)
            if (F32IN) {
                const float* X = (const float*)Xv;
                float4 v0 = *(const float4*)(X + (size_t)gr * K + kt * BK + c * 8);
                float4 v1 = *(const float4*)(X + (size_t)gr * K + kt * BK + c * 8 + 4);
                int4 pk;
                pk.x = (int)cvt_pk_bf16(v0.x, v0.y);
                pk.y = (int)cvt_pk_bf16(v0.z, v0.w);
                pk.z = (int)cvt_pk_bf16(v1.x, v1.y);
                pk.w = (int)cvt_pk_bf16(v1.z, v1.w);
                *(int4*)(At + r * BK + (c ^ (r & 7)) * 8) = pk;
            } else {
                const u16* X = (const u16*)Xv;
                int4 v = *(const int4*)(X + (size_t)gr * K + kt * BK + c * 8);
                *(int4*)(At + r * BK + (c ^ (r & 7)) * 8) = v;
            }
        }
        __syncthreads();
#pragma unroll
        for (int ks = 0; ks < 2; ++ks) {
            short8 bfr[DO / 16];
            int kq = kt * 8 + ks * 4 + quad;
#pragma unroll
            for (int ct = 0; ct < DO / 16; ++ct)
                bfr[ct] = *(const short8*)(Wf + ((size_t)kq * DO + ct * 16 + l16) * 8);
#pragma unroll
            for (int rt = 0; rt < 2; ++rt) {
                int row = wave * 32 + rt * 16 + l16;
                int unit = (ks * 4 + quad) ^ (row & 7);
                short8 afr = *(const short8*)(At + row * BK + unit * 8);
#pragma unroll
                for (int ct = 0; ct < DO / 16; ++ct)
                    acc[rt][ct] =
                        __builtin_amdgcn_mfma_f32_16x16x32_bf16(afr, bfr[ct], acc[rt][ct], 0, 0, 0);
            }
        }
    }
    // Epilogue. C/D layout: col = ct*16 + l16, row = quad*4 + r  [m89/m91 verified].
    float asv[DO / 16], adv[DO / 16];
#pragma unroll
    for (int ct = 0; ct < DO / 16; ++ct) {
        asv[ct] = a_src[ct * 16 + l16];
        adv[ct] = a_dst[ct * 16 + l16];
    }
#pragma unroll
    for (int rt = 0; rt < 2; ++rt)
#pragma unroll
        for (int r = 0; r < 4; ++r) {
            int grow = row0 + wave * 32 + rt * 16 + quad * 4 + r;
            bool ok = grow < nrow;
            float ps = 0.f, pd = 0.f;
#pragma unroll
            for (int ct = 0; ct < DO / 16; ++ct) {
                float v = acc[rt][ct][r];
                ps = fmaf(v, asv[ct], ps);
                pd = fmaf(v, adv[ct], pd);
                if (ok) ((u16*)Hv)[(size_t)grow * DO + ct * 16 + l16] = f2bf(v);
            }
            // reduce over the 16-lane col group (xor bits 0-3 stay within quad)
#pragma unroll
            for (int o = 1; o < 16; o <<= 1) {
                ps += __shfl_xor(ps, o);
                pd += __shfl_xor(pd, o);
            }
            if (ok && l16 == 0) {
                AS[grow] = ps;
                AD[grow] = pd;
            }
        }
}

// standalone GEMM (layers 2/3)
template <int K, int DO, bool F32IN>
__global__ __launch_bounds__(256, 2) void gemm_k(const void* __restrict__ Xv,
                                                 const u16* __restrict__ Wf,
                                                 void* __restrict__ Hv,
                                                 const float* __restrict__ a_src,
                                                 const float* __restrict__ a_dst,
                                                 float* __restrict__ AS,
                                                 float* __restrict__ AD, int nrow) {
    gemm_body<K, DO, F32IN>(Xv, Wf, Hv, a_src, a_dst, AS, AD, nrow, blockIdx.x);
}

// ---------------- fused layer-1 GEMM + CSR histogram/rank + W2/W3 prepack ----------------
// Blocks [0, GB): gemm1 tile. Blocks [GB, GB+nhist): hist+rank (+prepack W2/W3).
// Independent work on complementary pipes (MFMA/HBM-stream vs atomic/latency).
__global__ __launch_bounds__(256, 2) void gemm1_hist_k(
    const void* __restrict__ Xv, const u16* __restrict__ Wf, void* __restrict__ Hv,
    const float* __restrict__ a_src, const float* __restrict__ a_dst,
    float* __restrict__ AS, float* __restrict__ AD, int nrow, int GB,
    const int* __restrict__ dst, int* __restrict__ cnt, u16* __restrict__ rank, int E, int N,
    const float* __restrict__ W2, u16* __restrict__ Wf2,
    const float* __restrict__ W3, u16* __restrict__ Wf3) {
    if ((int)blockIdx.x < GB) {
        gemm_body<512, 128, true>(Xv, Wf, Hv, a_src, a_dst, AS, AD, nrow, blockIdx.x);
        return;
    }
    int e = (blockIdx.x - GB) * 256 + threadIdx.x;
    if (e < E) {
        int d = dst[e];
        d = d < 0 ? 0 : (d >= N ? N - 1 : d);
        rank[e] = (u16)atomicAdd(&cnt[d], 1);
    }
    const int T2 = 128 * 128, T3 = 128 * 64;
    if (e < T2) prepack1(W2, Wf2, 128, e);
    else if (e < T2 + T3) prepack1(W3, Wf3, 64, e - T2);
}

// ---------------- scans ----------------
// block-level exclusive scan: 16 waves, shfl-scan per wave + cross-wave LDS combine
__global__ void scan1_k(const int* __restrict__ cnt, int* __restrict__ excl,
                        int* __restrict__ aux, int N) {
    __shared__ int wsum[16];
    int t = threadIdx.x;
    int wv = t >> 6, ln = t & 63;
    int i = blockIdx.x * 1024 + t;
    int v = (i < N) ? cnt[i] : 0;
    int s = v;
    for (int off = 1; off < 64; off <<= 1) { int x = __shfl_up(s, off); if (ln >= off) s += x; }
    if (ln == 63) wsum[wv] = s;
    __syncthreads();
    if (wv == 0) {
        int ws = (ln < 16) ? wsum[ln] : 0;
        int ss = ws;
        for (int off = 1; off < 16; off <<= 1) { int x = __shfl_up(ss, off); if (ln >= off) ss += x; }
        if (ln < 16) wsum[ln] = ss - ws;  // exclusive wave offsets
    }
    __syncthreads();
    int base = wsum[wv];
    if (i < N) excl[i] = base + s - v;
    if (t == 1023) aux[blockIdx.x] = base + s;
}

__global__ void scan2_k(int* __restrict__ aux, int nb) {
    int lane = threadIdx.x;  // single block of 64; nb <= 128
    int v0 = (lane < nb) ? aux[lane] : 0;
    int v1 = (lane + 64 < nb) ? aux[lane + 64] : 0;
    int s0 = v0;
    for (int off = 1; off < 64; off <<= 1) { int x = __shfl_up(s0, off); if (lane >= off) s0 += x; }
    int total0 = __shfl(s0, 63);
    int s1 = v1;
    for (int off = 1; off < 64; off <<= 1) { int x = __shfl_up(s1, off); if (lane >= off) s1 += x; }
    if (lane < nb) aux[lane] = s0 - v0;
    if (lane + 64 < nb) aux[lane + 64] = total0 + s1 - v1;
}

__global__ void scan3_k(const int* __restrict__ excl, const int* __restrict__ aux,
                        int* __restrict__ offs, int N, int E) {
    int i = blockIdx.x * 1024 + threadIdx.x;
    if (i < N) {
        offs[i] = excl[i] + aux[blockIdx.x];
    } else if (i == N) {
        offs[N] = E;
    }
}

// Atomic-free single-pass scatter: esrc[offs[d] + rank[e]] = src[e].
// Every esrc byte is written exactly once; line-allocation overhead is bounded by
// |esrc| = 6.4 MB regardless of access order, so no windowed passes needed.
__global__ __launch_bounds__(256) void scatter1_k(const int* __restrict__ src,
                                                  const int* __restrict__ dst,
                                                  const u16* __restrict__ rank,
                                                  const int* __restrict__ offs,
                                                  int* __restrict__ esrc, int E, int N) {
    int e = blockIdx.x * 256 + threadIdx.x;
    if (e < E) {
        int d = dst[e];
        d = d < 0 ? 0 : (d >= N ? N - 1 : d);
        int s = src[e];
        s = s < 0 ? 0 : (s >= N ? N - 1 : s);
        esrc[offs[d] + (int)rank[e]] = s;
    }
}

// ---------------- fused segment softmax + aggregate (one wave per dst node) ----------------
// Gather scheme: 16 lanes own one edge-row; a wave processes 4 edges per load
// instruction. Row = 256B (DO=128 bf16) or 128B (DO=64 bf16).
// HB: h rows bf16 (else fp32). OUTB: write bf16 packed (else fp32).
template <int DO, bool HB, bool OUTB>
__global__ __launch_bounds__(256) void agg_k(const void* __restrict__ Hv,
                                             const float* __restrict__ AS,
                                             const float* __restrict__ AD,
                                             const int* __restrict__ offs,
                                             const int* __restrict__ esrc,
                                             const float* __restrict__ bias,
                                             void* __restrict__ OUT, int N) {
    constexpr int NC = HB ? DO / 16 : 4;  // floats per lane slice (bf16: DO/16, fp32: 4)
    const int wave = threadIdx.x >> 6, lane = threadIdx.x & 63;
    const int sub = lane >> 4, l16 = lane & 15;
    const int d = blockIdx.x * 4 + wave;
    if (d >= N) return;
    const int o0 = offs[d];
    const int deg = offs[d + 1] - o0;  // real in-edges
    const int tot = deg + 1;           // + self loop
    const float ad = AD[d];

    float acc[NC];
#pragma unroll
    for (int c = 0; c < NC; ++c) acc[c] = 0.f;

    // gather one row-slice of row sl with weight wl
    auto gath = [&](float wl, int sl) {
        if (HB) {
            if (DO == 128) {
                uint4 hv = ((const uint4*)Hv)[(size_t)sl * 16 + l16];
                u32 p[4] = {hv.x, hv.y, hv.z, hv.w};
#pragma unroll
                for (int c = 0; c < 4; ++c) {
                    acc[2 * c] = fmaf(wl, bf2f((u16)p[c]), acc[2 * c]);
                    acc[2 * c + 1] = fmaf(wl, bf2f((u16)(p[c] >> 16)), acc[2 * c + 1]);
                }
            } else {
                uint2 hv = ((const uint2*)Hv)[(size_t)sl * 16 + l16];
                acc[0] = fmaf(wl, bf2f((u16)hv.x), acc[0]);
                acc[1] = fmaf(wl, bf2f((u16)(hv.x >> 16)), acc[1]);
                acc[2] = fmaf(wl, bf2f((u16)hv.y), acc[2]);
                acc[3] = fmaf(wl, bf2f((u16)(hv.y >> 16)), acc[3]);
            }
        } else {
            float4 hv = ((const float4*)Hv)[(size_t)sl * 16 + l16];
            acc[0] = fmaf(wl, hv.x, acc[0]);
            acc[1] = fmaf(wl, hv.y, acc[1]);
            acc[2] = fmaf(wl, hv.z, acc[2]);
            acc[3] = fmaf(wl, hv.w, acc[3]);
        }
    };
    // 4 edges starting at l: sub-group `sub` takes edge l+sub (w,s live in lane idx)
    auto quad = [&](float w, int s, int l, int lim) {
        int idx = l + sub;
        int cl = idx < lim ? idx : lim - 1;
        float wv = __shfl(w, cl);  // ds_bpermute, per-lane src index
        int sl = __shfl(s, cl);
        gath(idx < lim ? wv : 0.f, sl);
    };

    if (tot <= 64) {
        // ---- fast path: whole segment resident in one wave, single gather pass ----
        int s = (lane < deg) ? esrc[o0 + lane] : d;  // lane==deg -> self loop
        bool valid = lane < tot;
        float lg = AS[s] + ad;
        lg = lg > 0.f ? lg : lg * 0.2f;
        float lgv = valid ? lg : -1e30f;
        float m = lgv;
        for (int o = 32; o; o >>= 1) m = fmaxf(m, __shfl_xor(m, o));
        float e = valid ? __expf(lg - m) : 0.f;
        float sum = e;
        for (int o = 32; o; o >>= 1) sum += __shfl_xor(sum, o);
        float w = e * (1.f / sum);
        for (int l = 0; l < tot; l += 16) {
#pragma unroll
            for (int g = 0; g < 4; ++g)
                if (l + g * 4 < tot) quad(w, s, l + g * 4, tot);
        }
    } else {
        // ---- general path (deg > 63, rare at avg deg 16): 3-pass ----
        float mx = -1e30f;
        for (int i = lane; i < tot; i += 64) {
            int s = (i < deg) ? esrc[o0 + i] : d;
            float lg = AS[s] + ad;
            lg = lg > 0.f ? lg : lg * 0.2f;
            mx = fmaxf(mx, lg);
        }
        for (int o = 32; o; o >>= 1) mx = fmaxf(mx, __shfl_xor(mx, o));
        float sum = 0.f;
        for (int i = lane; i < tot; i += 64) {
            int s = (i < deg) ? esrc[o0 + i] : d;
            float lg = AS[s] + ad;
            lg = lg > 0.f ? lg : lg * 0.2f;
            sum += __expf(lg - mx);
        }
        for (int o = 32; o; o >>= 1) sum += __shfl_xor(sum, o);
        const float inv = 1.f / sum;
        for (int c0 = 0; c0 < tot; c0 += 64) {
            int i = c0 + lane;
            float w = 0.f;
            int s = d;
            if (i < tot) {
                s = (i < deg) ? esrc[o0 + i] : d;
                float lg = AS[s] + ad;
                lg = lg > 0.f ? lg : lg * 0.2f;
                w = __expf(lg - mx) * inv;
            }
            int cn = tot - c0;
            cn = cn < 64 ? cn : 64;
            for (int l = 0; l < cn; l += 16) {
#pragma unroll
                for (int g = 0; g < 4; ++g)
                    if (l + g * 4 < cn) quad(w, s, l + g * 4, cn);
            }
        }
    }

    // fold the 4 edge-subsets
#pragma unroll
    for (int c = 0; c < NC; ++c) {
        acc[c] += __shfl_xor(acc[c], 16);
        acc[c] += __shfl_xor(acc[c], 32);
    }

    // epilogue: + bias, leaky_relu(0.25), store (sub==0 lanes write their slice)
    if (sub == 0) {
        if (DO == 128) {
            u32 pk[4];
            float fv[8];
#pragma unroll
            for (int c = 0; c < 8; ++c) {
                float v = acc[c] + bias[l16 * 8 + c];
                fv[c] = v > 0.f ? v : v * 0.25f;
            }
            if (OUTB) {
#pragma unroll
                for (int c = 0; c < 4; ++c)
                    pk[c] = (u32)f2bf(fv[2 * c]) | ((u32)f2bf(fv[2 * c + 1]) << 16);
                ((uint4*)OUT)[(size_t)d * 16 + l16] = uint4{pk[0], pk[1], pk[2], pk[3]};
            } else {
                float4 o0v = float4{fv[0], fv[1], fv[2], fv[3]};
                float4 o1v = float4{fv[4], fv[5], fv[6], fv[7]};
                ((float4*)OUT)[(size_t)d * 32 + l16 * 2] = o0v;
                ((float4*)OUT)[(size_t)d * 32 + l16 * 2 + 1] = o1v;
            }
        } else {
            float4 v;
            v.x = acc[0] + bias[l16 * 4 + 0];
            v.y = acc[1] + bias[l16 * 4 + 1];
            v.z = acc[2] + bias[l16 * 4 + 2];
            v.w = acc[3] + bias[l16 * 4 + 3];
            v.x = v.x > 0.f ? v.x : v.x * 0.25f;
            v.y = v.y > 0.f ? v.y : v.y * 0.25f;
            v.z = v.z > 0.f ? v.z : v.z * 0.25f;
            v.w = v.w > 0.f ? v.w : v.w * 0.25f;
            if (OUTB) {
                u32 p0 = (u32)f2bf(v.x) | ((u32)f2bf(v.y) << 16);
                u32 p1 = (u32)f2bf(v.z) | ((u32)f2bf(v.w) << 16);
                ((uint2*)OUT)[(size_t)d * 16 + l16] = uint2{p0, p1};
            } else {
                ((float4*)OUT)[(size_t)d * 16 + l16] = v;
            }
        }
    }
}

// ---------------- launch ----------------

extern "C" void kernel_launch(void* const* d_in, const int* in_sizes, int n_in,
                              void* d_out, int out_size, void* d_ws, size_t ws_size,
                              hipStream_t stream) {
    const int N = in_sizes[0] / 512;  // 100000
    const int E = in_sizes[1] / 2;    // 1600000

    const float* data = (const float*)d_in[0];
    const int* adj = (const int*)d_in[1];
    const float* W1 = (const float*)d_in[2];
    const float* as1 = (const float*)d_in[3];
    const float* ad1 = (const float*)d_in[4];
    const float* b1 = (const float*)d_in[5];
    const float* W2 = (const float*)d_in[6];
    const float* as2 = (const float*)d_in[7];
    const float* ad2 = (const float*)d_in[8];
    const float* b2 = (const float*)d_in[9];
    const float* W3 = (const float*)d_in[10];
    const float* as3 = (const float*)d_in[11];
    const float* ad3 = (const float*)d_in[12];
    const float* b3 = (const float*)d_in[13];

    // ---- workspace carve + budget check ----
    char* ws = (char*)d_ws;
    size_t need = 0;
    auto carve = [&](size_t bytes) {
        void* p = (void*)(ws + need);
        need += (bytes + 255) & ~(size_t)255;
        return p;
    };
    int* esrc = (int*)carve((size_t)E * 4);
    int* offs = (int*)carve((size_t)(N + 1) * 4);
    int* cnt = (int*)carve((size_t)N * 4);
    int* excl = (int*)carve((size_t)N * 4);
    int* aux = (int*)carve(1024);
    float* AS = (float*)carve((size_t)N * 4);
    float* AD = (float*)carve((size_t)N * 4);
    u16* rank = (u16*)carve((size_t)E * 2);      // dedicated: hist runs concurrent w/ gemm1
    u16* Hb = (u16*)carve((size_t)N * 128 * 2);  // bf16 h (all 3 layers; L3 uses 64 cols)
    u16* x1 = (u16*)carve((size_t)N * 128 * 2);  // bf16 next-layer input
    u16* x2 = x1;                                // x1 dead after layer-2 GEMM
    u16* Wf1 = (u16*)carve(512 * 128 * 2);
    u16* Wf2 = (u16*)carve(128 * 128 * 2);
    u16* Wf3 = (u16*)carve(128 * 64 * 2);

    if (need > ws_size) {
        // Diagnostic signature: absmax == ref absmax (0.2373) => ws too small.
        zero_out_k<<<(out_size + 255) / 256, 256, 0, stream>>>((float*)d_out, out_size);
        return;
    }

    const int* srcl = adj;
    const int* dstl = adj + E;

    const int gblk = (N + 127) / 128;
    const int nblk = (N + 3) / 4;
    const int nhist = (E + 255) / 256;

    // ---- W1 prepack (tiny; gemm1 dependency) ----
    hipMemsetAsync(cnt, 0, (size_t)N * 4, stream);
    prepack_w1_k<<<(512 * 128 + 255) / 256, 256, 0, stream>>>(W1, Wf1);

    // ---- fused: layer-1 GEMM || CSR hist+rank || W2/W3 prepack ----
    gemm1_hist_k<<<gblk + nhist, 256, 0, stream>>>(data, Wf1, Hb, as1, ad1, AS, AD, N, gblk,
                                                   dstl, cnt, rank, E, N, W2, Wf2, W3, Wf3);

    // ---- scans + single-pass rank-scatter ----
    int nb = (N + 1023) / 1024;
    scan1_k<<<nb, 1024, 0, stream>>>(cnt, excl, aux, N);
    scan2_k<<<1, 64, 0, stream>>>(aux, nb);
    scan3_k<<<nb, 1024, 0, stream>>>(excl, aux, offs, N, E);
    scatter1_k<<<nhist, 256, 0, stream>>>(srcl, dstl, rank, offs, esrc, E, N);

    // ---- layer 1 agg ----
    agg_k<128, true, true><<<nblk, 256, 0, stream>>>(Hb, AS, AD, offs, esrc, b1, x1, N);
    // ---- layer 2 ----
    gemm_k<128, 128, false><<<gblk, 256, 0, stream>>>(x1, Wf2, Hb, as2, ad2, AS, AD, N);
    agg_k<128, true, true><<<nblk, 256, 0, stream>>>(Hb, AS, AD, offs, esrc, b2, x2, N);
    // ---- layer 3: h3 bf16 (128B rows) ----
    gemm_k<128, 64, false><<<gblk, 256, 0, stream>>>(x2, Wf3, Hb, as3, ad3, AS, AD, N);
    agg_k<64, true, false><<<nblk, 256, 0, stream>>>(Hb, AS, AD, offs, esrc, b3, d_out, N);
}